// Round 2
// baseline (87.999 us; speedup 1.0000x reference)
//
#include <hip/hip_runtime.h>

// AssignYolo: N=262144 anchors, M=128 gts, THRESH=0.3
// Layout: 256-thread blocks = 4 waves; each wave handles 64 consecutive anchors
// (scalar s_load broadcast via readfirstlane). Lane l owns gt[l] and gt[l+64],
// so the per-gt argmax needs no cross-lane reduction; the row threshold is one
// ballot per anchor. Division is default (IEEE correctly-rounded) f32 to
// bitwise-match the numpy reference's rounded quotients; argmax tie-break =
// smallest anchor index via packed key.
//
// Epilogue: per-block LDS reduce (4 waves) -> atomicMax into bb[128] in d_ws
// using BIASED keys: ((iou_bits | 0xC0000000) << 32) | (0xFFFFFFFF - idx).
// iou in [0,1] -> iou_bits <= 0x3F800000 < 0x40000000, so OR 0xC0000000 is a
// strictly order-preserving +bias. Every real key >= 0xC0000000_00000000,
// which exceeds both 0x0 and the harness's 0xAAAA.. ws poison -> no init
// kernel needed. k_final (1 block) converts the 128 winners to claims.

static __device__ __forceinline__ unsigned long long umax64(unsigned long long a,
                                                            unsigned long long b) {
    return a > b ? a : b;
}

static __device__ __forceinline__ unsigned long long packbest(float iou, unsigned idx) {
    // Low word = 0xFFFFFFFF - idx: ties in iou resolve to the SMALLEST index,
    // matching jnp.argmax(axis=0) first-occurrence semantics.
    return ((unsigned long long)(__float_as_uint(iou) | 0xC0000000u) << 32)
         | (unsigned long long)(0xFFFFFFFFu - idx);
}

__global__ __launch_bounds__(256) void k_main(const float4* __restrict__ anchors,
                                              const float4* __restrict__ gt,
                                              int* __restrict__ assign,
                                              unsigned long long* __restrict__ bb) {
    const int lane = threadIdx.x & 63;
    const int wave = threadIdx.x >> 6;

    // Each lane owns two gts: lane and lane+64 (M == 128).
    const float4 g0 = gt[lane];
    const float4 g1 = gt[lane + 64];
    const float ga0 = (g0.z - g0.x) * (g0.w - g0.y);
    const float ga1 = (g1.z - g1.x) * (g1.w - g1.y);

    const int base = (blockIdx.x * 4 + wave) * 64;
    // Provably wave-uniform base -> compiler emits scalar s_load_dwordx4 for
    // the per-iteration anchor, issuing on the scalar pipe instead of VMEM.
    const int ubase = __builtin_amdgcn_readfirstlane(base);

    // Per-lane column best. Init (iou=0, idx=0) reproduces argmax-of-all-zeros -> 0.
    float bi0 = 0.0f, bi1 = 0.0f;
    unsigned bx0 = 0u, bx1 = 0u;
    unsigned long long rowmask = 0ull;  // wave-uniform: bit j = anchor base+j has iou>=0.3

#pragma unroll 8
    for (int j = 0; j < 64; ++j) {
        const float4 a = anchors[ubase + j];  // scalar load, broadcast

        float w0 = fmaxf(fminf(a.z, g0.z) - fmaxf(a.x, g0.x), 0.0f);
        float h0 = fmaxf(fminf(a.w, g0.w) - fmaxf(a.y, g0.y), 0.0f);
        float w1 = fmaxf(fminf(a.z, g1.z) - fmaxf(a.x, g1.x), 0.0f);
        float h1 = fmaxf(fminf(a.w, g1.w) - fmaxf(a.y, g1.y), 0.0f);
        float in0 = w0 * h0;
        float in1 = w1 * h1;

        // ~29% of anchors overlap no gt across the whole wave: wave-uniform
        // skip of the correctly-rounded-division block.
        if (__ballot((in0 > 0.0f) || (in1 > 0.0f)) != 0ull) {
            float aa = (a.z - a.x) * (a.w - a.y);
            // Order of ops matches reference: (area_a + area_g) - inter, then /.
            float iou0 = in0 / ((aa + ga0) - in0);
            float iou1 = in1 / ((aa + ga1) - in1);
            const int aj = ubase + j;
            // Strictly-greater keeps the earliest index within a lane (j ascending).
            if (iou0 > bi0) { bi0 = iou0; bx0 = (unsigned)aj; }
            if (iou1 > bi1) { bi1 = iou1; bx1 = (unsigned)aj; }
            unsigned long long rb = __ballot((iou0 >= 0.3f) || (iou1 >= 0.3f));
            if (rb != 0ull) rowmask |= (1ull << j);
        }
    }

    // Coalesced row-result store: lane l writes anchor base+l using bit l.
    assign[base + lane] = ((rowmask >> lane) & 1ull) ? -2 : -1;

    // Reduce the 4 waves' per-gt bests via LDS, then one atomicMax per gt per block.
    __shared__ unsigned long long red[4][128];
    red[wave][lane] = packbest(bi0, bx0);
    red[wave][lane + 64] = packbest(bi1, bx1);
    __syncthreads();

    const int t = threadIdx.x;
    if (t < 128) {
        unsigned long long m = umax64(umax64(red[0][t], red[1][t]),
                                      umax64(red[2][t], red[3][t]));
        atomicMax(&bb[t], m);  // biased keys beat 0x0 and 0xAA.. poison alike
    }
}

// One block: convert the 128 per-gt winners into claims on assign.
__global__ __launch_bounds__(128) void k_final(const unsigned long long* __restrict__ bb,
                                               int* __restrict__ assign) {
    const int g = threadIdx.x;
    unsigned idx = 0xFFFFFFFFu - (unsigned)(bb[g] & 0xFFFFFFFFull);
    // gt ids >= 0 > {-1,-2}; duplicate claims resolved by max (higher gt wins),
    // exactly matching assign.at[col_arg].max(arange(M)).
    atomicMax(assign + idx, g);
}

extern "C" void kernel_launch(void* const* d_in, const int* in_sizes, int n_in,
                              void* d_out, int out_size, void* d_ws, size_t ws_size,
                              hipStream_t stream) {
    const float4* anchors = (const float4*)d_in[0];
    const float4* gt = (const float4*)d_in[1];
    int* assign = (int*)d_out;  // reference output dtype is int32

    const int n = in_sizes[0] / 4;       // 262144
    const int nblocks = n / 256;         // 1024

    unsigned long long* bb = (unsigned long long*)d_ws;  // 128 slots = 1 KB

    k_main<<<nblocks, 256, 0, stream>>>(anchors, gt, assign, bb);
    k_final<<<1, 128, 0, stream>>>(bb, assign);
}